// Round 11
// baseline (1203.522 us; speedup 1.0000x reference)
//
#include <hip/hip_runtime.h>
#include <hip/hip_bf16.h>
#include <stdint.h>

typedef unsigned short u16;
typedef unsigned int   u32;
typedef float f32x4  __attribute__((ext_vector_type(4)));
typedef short bf16x8 __attribute__((ext_vector_type(8)));

#define NSEQ 800
#define TOUT 12
#define NC   9
#define LOG2E  1.44269504088896340736f
#define LOG2E2 2.88539008177792681472f

// ---- Round-28: transposed GEMM — h lives in registers, no LDS round-trip ----
// R27 counters proved pipe-SUM (VALU 525 + LDS 430 + MFMA 136 ~= 938 us): the
// h ds_write->ds_read sat ON the recurrence chain, serializing LDS vs VALU.
// R28 computes G^T = W^T h^T ([hid x seq]): output lane (q,n) holds hid
// ht*16+q*4+reg of seq n, and with contraction map
//   hid_src(k=q*8+j, tile) = (j&3)*16 + q*4 + (j>>2) + 2*tile
// the next step's B-operand (h^T) is EXACTLY the lane's own hO values ->
// 8 pkbf packs replace 4 ds_writes + 2 ds_reads + 2 lgkm drains on the chain.
// W becomes the A operand (x staging identical — A/B frags share lane maps,
// proven by the old verified kernel; whh staging gets the j-remap above).
// Remaining 36 W-frag reads/step are loop-invariant, off-chain, pipelinable
// under the previous step's pointwise: pipe-sum -> pipe-max within one wave.
// Biases become q-indexed (64 VGPR) -> launch_bounds(512,1) (cap 256;
// residency stays 2 waves/SIMD — register-locked, accepted).
// Decoder: reduce = 16 fma + 2 shfl_xor; lv feedback lane-local.
#define BH_OFF 0
#define BX_OFF 24576
#define LDS_TOTAL 36864

__device__ __forceinline__ u16 f2bf(float f){ union{float f;u32 i;}v; v.f=f; u32 x=v.i; return (u16)((x + 0x7fffu + ((x>>16)&1u))>>16); }
__device__ __forceinline__ u32 pkbf(float a, float b){
  union{ __hip_bfloat162 h2; u32 u; } v;
  v.h2 = __float22bfloat162_rn(float2{a,b});
  return v.u;
}

union BXU { uint4 u; bf16x8 v; };
union PKU { u32 w[4]; bf16x8 v; };

__global__ __launch_bounds__(512, 1) void rnn_kernel(
  const float* __restrict__ X,
  const float* __restrict__ cw2, const float* __restrict__ cw3, const float* __restrict__ cw4,
  const float* __restrict__ cbv,
  const float* __restrict__ Ewih, const float* __restrict__ Ewhh,
  const float* __restrict__ Ebih, const float* __restrict__ Ebhh,
  const float* __restrict__ Dwih, const float* __restrict__ Dwhh,
  const float* __restrict__ Dbih, const float* __restrict__ Dbhh,
  const float* __restrict__ Lw,   const float* __restrict__ Lb,
  const float* __restrict__ emb,
  float* __restrict__ out)
{
  __shared__ char LDSC[LDS_TOTAL];
  const int tid = threadIdx.x;
  const int wv  = tid >> 6;      // wave id 0..7 -> seq group
  const int l   = tid & 63;
  const int q   = l >> 4;
  const int n   = l & 15;
  const int r   = blockIdx.y;
  const int seqb = blockIdx.x*128 + wv*16;   // this wave's 16 seqs

  const int Kc[NC]={2,2,2,3,3,3,4,4,4};
  const int Dc[NC]={1,2,4,1,2,4,1,2,4};
  const int K = Kc[r], D = Dc[r];
  const int L = 15 - (K-1)*D;

  // ---- cooperative whh staging as A-operand: A[row=hid_dst][k] per (gate,ht,tile)
  // group g = ks*12 + gate*4 + ht; lane fl: row = fl&15, k = (fl>>4)*8 + j
  // hid_src(k,ks) = ((j&3)<<4) | ((fl>>4)<<2) | (ks<<1) | (j>>2)
  auto stage_Bh = [&](const float* __restrict__ whh){
    #pragma unroll 1
    for (int it=0; it<3; it++){
      int slot = it*512 + tid;
      int g = slot >> 6, fl = slot & 63;
      int ks = g/12, nt = g%12;
      int col = nt*16 + (fl&15);          // hid_dst (with gate offset via nt)
      float s = (nt<8) ? LOG2E : LOG2E2;
      u32 w[4] = {0,0,0,0};
      #pragma unroll
      for (int j=0;j<8;j++){
        int hid = ((j&3)<<4) | ((fl>>4)<<2) | (ks<<1) | (j>>2);
        w[j>>1] |= (u32)f2bf(s * whh[col*64 + hid]) << ((j&1)*16);
      }
      *(uint4*)(LDSC + BH_OFF + slot*16) = uint4{w[0],w[1],w[2],w[3]};
    }
  };
  // ---- x-weight staging (unchanged: A/B frag lane maps are identical) ----
  auto stage_Bx_enc = [&](){
    const float* wih = Ewih + r*192*8;
    const float* cw  = (r<3) ? (cw2 + r*128) : (r<6) ? (cw3 + (r-3)*192) : (cw4 + (r-6)*256);
    #pragma unroll 1
    for (int it=0; it<2; it++){
      int slot = it*512 + tid;
      if (slot < 768){
        int g = slot >> 6, fl = slot & 63;
        int col = g*16 + (fl&15);
        int tap = fl>>4;
        float s = (g<8) ? LOG2E : LOG2E2;
        u32 w[4] = {0,0,0,0};
        if (tap < K){
          #pragma unroll
          for (int j=0;j<8;j++){
            float a = 0.f;
            #pragma unroll
            for (int o=0;o<8;o++) a += wih[col*8+o]*cw[(o*8+j)*K + tap];
            w[j>>1] |= (u32)f2bf(s*a) << ((j&1)*16);
          }
        }
        *(uint4*)(LDSC + BX_OFF + slot*16) = uint4{w[0],w[1],w[2],w[3]};
      }
    }
  };
  auto stage_Bx_dec = [&](){
    const float* dwih = Dwih + r*192;
    #pragma unroll 1
    for (int it=0; it<2; it++){
      int slot = it*512 + tid;
      if (slot < 768){
        int g = slot >> 6, fl = slot & 63;
        int col = g*16 + (fl&15);
        float s = (g<8) ? LOG2E : LOG2E2;
        u32 w0 = ((fl>>4)==0) ? (u32)f2bf(s*dwih[col]) : 0u;
        *(uint4*)(LDSC + BX_OFF + slot*16) = uint4{w0,0,0,0};
      }
    }
  };

  stage_Bh(Ewhh + (size_t)r*192*64);
  stage_Bx_enc();

  // ---- per-lane biases, q-indexed: hid = ht*16 + q*4 + reg (f32x4 per array,ht)
  f32x4 bRq[4], bZq[4], bNiq[4], bNhq[4];
  {
    const float* bi = Ebih + r*192; const float* bh2 = Ebhh + r*192;
    const float* wih = Ewih + r*192*8; const float* cb = cbv + r*8;
    #pragma unroll
    for (int ht=0; ht<4; ht++){
      #pragma unroll
      for (int rg=0; rg<4; rg++){
        int hid = ht*16 + q*4 + rg;
        float cR=0.f,cZ=0.f,cN=0.f;
        #pragma unroll
        for (int o=0;o<8;o++){
          cR += wih[hid*8+o]*cb[o];
          cZ += wih[(64+hid)*8+o]*cb[o];
          cN += wih[(128+hid)*8+o]*cb[o];
        }
        bRq[ht][rg]  = LOG2E  * (bi[hid]     + bh2[hid]     + cR);
        bZq[ht][rg]  = LOG2E  * (bi[64+hid]  + bh2[64+hid]  + cZ);
        bNiq[ht][rg] = LOG2E2 * (bi[128+hid]                + cN);
        bNhq[ht][rg] = LOG2E2 *                bh2[128+hid];
      }
    }
  }

  // h state: hO[ht][reg] = h[hid ht*16+q*4+reg][seq n]; packs hp0/hp1 = h^T B-frags
  float hO[4][4];
  #pragma unroll
  for (int ht=0;ht<4;ht++) for (int i=0;i<4;i++) hO[ht][i]=0.f;
  PKU hp0, hp1;
  hp0.w[0]=0;hp0.w[1]=0;hp0.w[2]=0;hp0.w[3]=0;
  hp1.w[0]=0;hp1.w[1]=0;hp1.w[2]=0;hp1.w[3]=0;

  // ---- one GRU step: MFMA(A=W from LDS, B=h-pack/x in regs) -> pointwise -> repack
#define STEP_CORE(AX) do{ \
    bf16x8 ax_ = (AX); \
    _Pragma("unroll") \
    for (int ht=0; ht<4; ht++){ \
      bf16x8 bR0 = *(const bf16x8*)(LDSC + BH_OFF + ((      ht)*64 + l)*16); \
      bf16x8 bR1 = *(const bf16x8*)(LDSC + BH_OFF + ((12  + ht)*64 + l)*16); \
      bf16x8 bZ0 = *(const bf16x8*)(LDSC + BH_OFF + (( 4 + ht)*64 + l)*16); \
      bf16x8 bZ1 = *(const bf16x8*)(LDSC + BH_OFF + ((16  + ht)*64 + l)*16); \
      bf16x8 bN0 = *(const bf16x8*)(LDSC + BH_OFF + (( 8 + ht)*64 + l)*16); \
      bf16x8 bN1 = *(const bf16x8*)(LDSC + BH_OFF + ((20  + ht)*64 + l)*16); \
      bf16x8 xR  = *(const bf16x8*)(LDSC + BX_OFF + ((      ht)*64 + l)*16); \
      bf16x8 xZ  = *(const bf16x8*)(LDSC + BX_OFF + (( 4 + ht)*64 + l)*16); \
      bf16x8 xN  = *(const bf16x8*)(LDSC + BX_OFF + (( 8 + ht)*64 + l)*16); \
      f32x4 aR  = bRq[ht]; \
      f32x4 aZ  = bZq[ht]; \
      f32x4 aNi = bNiq[ht]; \
      f32x4 aNh = bNhq[ht]; \
      aR = __builtin_amdgcn_mfma_f32_16x16x32_bf16(bR0, hp0.v, aR,0,0,0); \
      aR = __builtin_amdgcn_mfma_f32_16x16x32_bf16(bR1, hp1.v, aR,0,0,0); \
      aR = __builtin_amdgcn_mfma_f32_16x16x32_bf16(xR,  ax_,   aR,0,0,0); \
      aZ = __builtin_amdgcn_mfma_f32_16x16x32_bf16(bZ0, hp0.v, aZ,0,0,0); \
      aZ = __builtin_amdgcn_mfma_f32_16x16x32_bf16(bZ1, hp1.v, aZ,0,0,0); \
      aZ = __builtin_amdgcn_mfma_f32_16x16x32_bf16(xZ,  ax_,   aZ,0,0,0); \
      aNh= __builtin_amdgcn_mfma_f32_16x16x32_bf16(bN0, hp0.v, aNh,0,0,0); \
      aNh= __builtin_amdgcn_mfma_f32_16x16x32_bf16(bN1, hp1.v, aNh,0,0,0); \
      aNi= __builtin_amdgcn_mfma_f32_16x16x32_bf16(xN,  ax_,   aNi,0,0,0); \
      _Pragma("unroll") \
      for (int i=0;i<4;i++){ \
        float rr = __builtin_amdgcn_rcpf(1.f + __builtin_amdgcn_exp2f(-aR[i])); \
        float zz = __builtin_amdgcn_rcpf(1.f + __builtin_amdgcn_exp2f(-aZ[i])); \
        float y  = aNi[i] + rr*aNh[i]; \
        float nn = 1.f - 2.f*__builtin_amdgcn_rcpf(__builtin_amdgcn_exp2f(y) + 1.f); \
        hO[ht][i] = nn + zz*(hO[ht][i]-nn); \
      } \
    } \
    hp0.w[0]=pkbf(hO[0][0],hO[1][0]); hp0.w[1]=pkbf(hO[2][0],hO[3][0]); \
    hp0.w[2]=pkbf(hO[0][1],hO[1][1]); hp0.w[3]=pkbf(hO[2][1],hO[3][1]); \
    hp1.w[0]=pkbf(hO[0][2],hO[1][2]); hp1.w[1]=pkbf(hO[2][2],hO[3][2]); \
    hp1.w[2]=pkbf(hO[0][3],hO[1][3]); hp1.w[3]=pkbf(hO[2][3],hO[3][3]); \
  }while(0)

  // ---------- encoder: NO barriers in loop; x prefetched one step ahead ----------
  // ax is the x B-frag: element j = x[seq n][k=q*8+j] (same values as old A-frag)
  const float* xb = X + (size_t)(seqb + n)*120 + ((q<K)? q:0)*D*8;
  float4 c0 = *(const float4*)(xb);
  float4 c1 = *(const float4*)(xb + 4);
  __syncthreads();   // staging visible
  #pragma unroll 1
  for (int t=0; t<L; t++){
    int tn = (t+1 < L) ? (t+1) : t;
    float4 n0 = *(const float4*)(xb + tn*8);
    float4 n1 = *(const float4*)(xb + tn*8 + 4);
    BXU a;
    a.u.x = __builtin_amdgcn_perm(__float_as_uint(c0.y), __float_as_uint(c0.x), 0x07060302u);
    a.u.y = __builtin_amdgcn_perm(__float_as_uint(c0.w), __float_as_uint(c0.z), 0x07060302u);
    a.u.z = __builtin_amdgcn_perm(__float_as_uint(c1.y), __float_as_uint(c1.x), 0x07060302u);
    a.u.w = __builtin_amdgcn_perm(__float_as_uint(c1.w), __float_as_uint(c1.z), 0x07060302u);
    STEP_CORE(a.v);
    c0 = n0; c1 = n1;
  }

  // ---------- decoder weight switch (2 barriers around restage) ----------
  __syncthreads();   // all waves done reading encoder weights
  stage_Bh(Dwhh + (size_t)r*192*64);
  stage_Bx_dec();
  {
    const float* bi = Dbih + r*192; const float* bh2 = Dbhh + r*192;
    #pragma unroll
    for (int ht=0; ht<4; ht++){
      #pragma unroll
      for (int rg=0; rg<4; rg++){
        int hid = ht*16 + q*4 + rg;
        bRq[ht][rg]  = LOG2E  * (bi[hid]     + bh2[hid]);
        bZq[ht][rg]  = LOG2E  * (bi[64+hid]  + bh2[64+hid]);
        bNiq[ht][rg] = LOG2E2 *  bi[128+hid];
        bNhq[ht][rg] = LOG2E2 *  bh2[128+hid];
      }
    }
  }
  f32x4 lwA[4];
  #pragma unroll
  for (int ht=0; ht<4; ht++)
    #pragma unroll
    for (int rg=0; rg<4; rg++)
      lwA[ht][rg] = Lw[r*64 + ht*16 + q*4 + rg];
  const float lb_ = Lb[r];
  float wgt;
  {
    int nb = (seqb + n) % NSEQ;
    float e[NC], mx = -1e30f;
    #pragma unroll
    for (int c=0;c<NC;c++){ e[c] = emb[nb*NC+c]; mx = fmaxf(mx, e[c]); }
    float sm = 0.f;
    #pragma unroll
    for (int c=0;c<NC;c++) sm += __expf(e[c]-mx);
    wgt = __expf(e[r]-mx) / sm;
  }
  float lv = X[(size_t)(seqb + n)*120 + 112];   // last0 for seq n (uniform over q)
  __syncthreads();   // dec staging visible

  // ---------- decoder: lv is lane-local (seq n); reduce = 16 fma + 2 shfl ----------
  #pragma unroll 1
  for (int t=0; t<TOUT; t++){
    BXU a; a.u = uint4{0,0,0,0};
    if (q==0) a.u.x = (u32)f2bf(lv);   // B[k=0][seq n] = lv
    STEP_CORE(a.v);
    float p = 0.f;
    #pragma unroll
    for (int ht=0; ht<4; ht++)
      #pragma unroll
      for (int i=0;i<4;i++)
        p += hO[ht][i]*lwA[ht][i];
    p += __shfl_xor(p, 16, 64);
    p += __shfl_xor(p, 32, 64);
    float v = p + lb_;
    lv = v;
    if (q==0) atomicAdd(out + (size_t)(seqb+n)*TOUT + t, wgt*v);
  }
}

extern "C" void kernel_launch(void* const* d_in, const int* in_sizes, int n_in,
                              void* d_out, int out_size, void* d_ws, size_t ws_size,
                              hipStream_t stream)
{
  float* out = (float*)d_out;
  hipMemsetAsync(out, 0, (size_t)out_size*sizeof(float), stream);

  dim3 g(NSEQ*64/128, NC);   // 400 x 9 blocks; 128 seqs/block, 8 seq-split waves
  rnn_kernel<<<g, 512, 0, stream>>>(
    (const float*)d_in[1],
    (const float*)d_in[2], (const float*)d_in[3], (const float*)d_in[4],
    (const float*)d_in[5],
    (const float*)d_in[6], (const float*)d_in[7], (const float*)d_in[8], (const float*)d_in[9],
    (const float*)d_in[10],(const float*)d_in[11],(const float*)d_in[12],(const float*)d_in[13],
    (const float*)d_in[14],(const float*)d_in[15],
    (const float*)d_in[16],
    out);
}